// Round 4
// baseline (153.487 us; speedup 1.0000x reference)
//
#include <hip/hip_runtime.h>
#include <hip/hip_bf16.h>

// Problem constants
#define BB 32
#define DD 64
#define HW 1024
#define NN 32768   // BB*HW
#define MM 1024

typedef _Float16 half8 __attribute__((ext_vector_type(8)));
typedef float    floatx4 __attribute__((ext_vector_type(4)));

#define MFMA16(a, b, c) __builtin_amdgcn_mfma_f32_16x16x32_f16((a), (b), (c), 0, 0, 0)

// lo-term scaling to dodge fp16-denormal flush in the MFMA pipe
#define LO_SCALE   2048.0f
#define LO_INV     (1.0f / 2048.0f)

// ---------------------------------------------------------------------------
// Kernel 1 (prep): swizzle -2*codebook into MFMA B-frag order (fp16 hi/lo),
// compute codebook squared norms, zero the loss slot.  16 blocks x 512.
// B frag for mfma_f32_16x16x32_f16: B[k][n]: n=lane&15, k=(lane>>4)*8+j.
// Storage: ch[((mtile*2+kstep)*64 + lane)*8 + j]; cl = lo * 2048.
// ---------------------------------------------------------------------------
__global__ void k_prep(const float* __restrict__ cb,
                       _Float16* __restrict__ ch,
                       _Float16* __restrict__ cl,
                       float* __restrict__ y2,
                       float* __restrict__ loss_slot) {
    int u = blockIdx.x * blockDim.x + threadIdx.x;   // 0..8191
    if (u == 0) *loss_slot = 0.0f;

    if (u < 64 * 2 * 64) {
        int lane  = u & 63;
        int kstep = (u >> 6) & 1;
        int mtile = u >> 7;
        int m  = mtile * 16 + (lane & 15);
        int d0 = kstep * 32 + ((lane >> 4) & 3) * 8;
        const float* src = cb + (size_t)m * DD + d0;
        half8 h, l;
#pragma unroll
        for (int j = 0; j < 8; ++j) {
            float x = -2.0f * src[j];
            _Float16 hi = (_Float16)x;
            _Float16 lo = (_Float16)((x - (float)hi) * LO_SCALE);
            h[j] = hi;
            l[j] = lo;
        }
        *(half8*)(ch + (size_t)u * 8) = h;
        *(half8*)(cl + (size_t)u * 8) = l;
    }

    if (u < MM) {
        const float4* c4 = (const float4*)(cb + (size_t)u * DD);
        float s = 0.f;
#pragma unroll
        for (int k = 0; k < 16; ++k) {
            float4 v = c4[k];
            s += v.x * v.x + v.y * v.y + v.z * v.z + v.w * v.w;
        }
        y2[u] = s;
    }
}

// ---------------------------------------------------------------------------
// Kernel 2 (main): fused distance + argmin + q_error + z_q + loss.
// 512 blocks x 512 threads (8 waves).  Block = 64 rows (b = blk>>4,
// hw0 = (blk&15)<<6).  Wave w holds A for ALL 4 ntiles (64 rows) and covers
// code-eighth w (8 mtiles = 128 codes) -> only 8 B-load iterations per wave,
// depth-2 prefetched (fully unrolled; ~2 L2 latencies in flight).
// acc1 = y2 + hi*hi ; acc2 = 2048*(hi*lo+lo*hi);
// dist_partial = acc1 + acc2/2048 (x2 added at epilogue, argmin-invariant).
// Same per-(row,code) MFMA sequence and argmin merge order as round 3 ->
// bit-identical results.
// ---------------------------------------------------------------------------
__global__ __launch_bounds__(512, 2) void k_main(const float* __restrict__ z,
                                                 const float* __restrict__ noise,
                                                 const _Float16* __restrict__ ch,
                                                 const _Float16* __restrict__ cl,
                                                 const float* __restrict__ y2,
                                                 float* __restrict__ zq,
                                                 float* __restrict__ ind_out,
                                                 float* __restrict__ loss_slot) {
    __shared__ float zt[64][65];     // zt[row(hw)][d]
    __shared__ float nt[64][65];     // nt[d][row(hw)]
    __shared__ float y2s[MM];
    __shared__ float x2p[64][8];
    __shared__ float snorm[64];
    __shared__ float scale_s[64];
    __shared__ float bestv_s[8][64]; // [code-eighth][row]
    __shared__ int   besti_s[8][64];
    __shared__ float partials[512];
    __shared__ float sq[4];

    const int t    = threadIdx.x;
    const int lane = t & 63;
    const int wv   = t >> 6;            // wave 0..7 = code-eighth
    const int quad = lane >> 4;         // 0..3
    const int col  = lane & 15;         // 0..15
    const int blk  = blockIdx.x;        // 0..511
    const int b    = blk >> 4;
    const int hw0  = (blk & 15) << 6;

    const float* zbase = z + ((size_t)b << 16) + hw0;

    // ---- stage z tile (coalesced), y2, noise tile (+ row norms) ----
    for (int i = t; i < 64 * 64; i += 512) {
        int d = i >> 6, r = i & 63;
        zt[r][d] = zbase[(size_t)d * HW + r];
    }
    for (int i = t; i < MM; i += 512) y2s[i] = y2[i];

    {
        const float4* noise4 = (const float4*)noise;
        const size_t base4 = (size_t)blk * 1024;     // 4096 floats / 4
#pragma unroll
        for (int k = 0; k < 2; ++k) {
            int v = t + 512 * k;                     // float4 index [0,1024)
            float4 vv = noise4[base4 + v];
            int c  = v >> 4;
            int d0 = (v & 15) << 2;
            nt[d0 + 0][c] = vv.x;
            nt[d0 + 1][c] = vv.y;
            nt[d0 + 2][c] = vv.z;
            nt[d0 + 3][c] = vv.w;
            float p = vv.x * vv.x + vv.y * vv.y + vv.z * vv.z + vv.w * vv.w;
            p += __shfl_xor(p, 1);
            p += __shfl_xor(p, 2);
            p += __shfl_xor(p, 4);
            p += __shfl_xor(p, 8);
            if ((t & 15) == 0) snorm[c] = p;
        }
    }
    __syncthreads();

    // ---- x2 partials + resident A fragments (hi/lo fp16), all 4 ntiles ----
    {
        int row = t & 63, seg = t >> 6;
        float s = 0.f;
#pragma unroll
        for (int j = 0; j < 8; ++j) {
            float v = zt[row][seg * 8 + j];
            s = __builtin_fmaf(v, v, s);
        }
        x2p[row][seg] = s;
    }

    // A frag: A[m][k]: m=lane&15, k=(lane>>4)*8+j.
    half8 ah[4][2], al[4][2];
#pragma unroll
    for (int ntl = 0; ntl < 4; ++ntl) {
        int row = ntl * 16 + col;
#pragma unroll
        for (int ks = 0; ks < 2; ++ks) {
            int d0 = ks * 32 + quad * 8;
            half8 h, l;
#pragma unroll
            for (int j = 0; j < 8; ++j) {
                float x = zt[row][d0 + j];
                _Float16 hi = (_Float16)x;
                _Float16 lo = (_Float16)((x - (float)hi) * LO_SCALE);
                h[j] = hi;
                l[j] = lo;
            }
            ah[ntl][ks] = h;
            al[ntl][ks] = l;
        }
    }
    __syncthreads();

    // ---- main loop: 8 mtiles per wave, depth-2 prefetched, fully unrolled ----
    const half8* ch8 = (const half8*)ch;
    const half8* cl8 = (const half8*)cl;

    float best[16];
    int   bmt[16];
#pragma unroll
    for (int s = 0; s < 16; ++s) { best[s] = 1e30f; bmt[s] = 0; }

    const int mt0 = wv * 8;

    half8 h0[8], l0[8], h1[8], l1[8];
    // preload iterations 0 and 1
#pragma unroll
    for (int i = 0; i < 2; ++i) {
        int mt = mt0 + i;
        h0[i] = ch8[((mt * 2 + 0) << 6) + lane];
        l0[i] = cl8[((mt * 2 + 0) << 6) + lane];
        h1[i] = ch8[((mt * 2 + 1) << 6) + lane];
        l1[i] = cl8[((mt * 2 + 1) << 6) + lane];
    }

#pragma unroll
    for (int i = 0; i < 8; ++i) {
        // prefetch i+2
        if (i + 2 < 8) {
            int mtp = mt0 + i + 2;
            h0[i + 2] = ch8[((mtp * 2 + 0) << 6) + lane];
            l0[i + 2] = cl8[((mtp * 2 + 0) << 6) + lane];
            h1[i + 2] = ch8[((mtp * 2 + 1) << 6) + lane];
            l1[i + 2] = cl8[((mtp * 2 + 1) << 6) + lane];
        }

        const int mt = mt0 + i;
        float y2v = y2s[(mt << 4) + col];
        floatx4 a1[4], a2[4];
#pragma unroll
        for (int ntl = 0; ntl < 4; ++ntl) {
            floatx4 i1 = {y2v, y2v, y2v, y2v};
            floatx4 i2 = {0.f, 0.f, 0.f, 0.f};
            a1[ntl] = i1;
            a2[ntl] = i2;
        }
#pragma unroll
        for (int ntl = 0; ntl < 4; ++ntl) {
            a1[ntl] = MFMA16(ah[ntl][0], h0[i], a1[ntl]);   // hi*hi (k 0..31)
            a2[ntl] = MFMA16(al[ntl][0], h0[i], a2[ntl]);   // lo*hi
            a2[ntl] = MFMA16(ah[ntl][0], l0[i], a2[ntl]);   // hi*lo
            a1[ntl] = MFMA16(ah[ntl][1], h1[i], a1[ntl]);   // hi*hi (k 32..63)
            a2[ntl] = MFMA16(al[ntl][1], h1[i], a2[ntl]);
            a2[ntl] = MFMA16(ah[ntl][1], l1[i], a2[ntl]);
        }
#pragma unroll
        for (int ntl = 0; ntl < 4; ++ntl) {
#pragma unroll
            for (int r = 0; r < 4; ++r) {
                float v = __builtin_fmaf(a2[ntl][r], LO_INV, a1[ntl][r]);
                int s = ntl * 4 + r;
                bool c = v < best[s];
                best[s] = c ? v : best[s];
                bmt[s]  = c ? mt : bmt[s];
            }
        }
    }

    // ---- per-wave cross-lane argmin (16 lanes share a row), then LDS ----
#pragma unroll
    for (int ntl = 0; ntl < 4; ++ntl) {
#pragma unroll
        for (int r = 0; r < 4; ++r) {
            int s = ntl * 4 + r;
            float v  = best[s];
            int  idx = bmt[s] * 16 + col;
#pragma unroll
            for (int mask = 1; mask <= 8; mask <<= 1) {
                float v2 = __shfl_xor(v, mask);
                int   i2 = __shfl_xor(idx, mask);
                if (v2 < v || (v2 == v && i2 < idx)) { v = v2; idx = i2; }
            }
            if (col == 0) {
                int rl = ntl * 16 + quad * 4 + r;
                bestv_s[wv][rl] = v;
                besti_s[wv][rl] = idx;
            }
        }
    }
    __syncthreads();

    // ---- merge code-eighths; write ind; compute scale in LDS ----
    if (t < 64) {
        float bv = bestv_s[0][t];
        int   bi = besti_s[0][t];
#pragma unroll
        for (int w = 1; w < 8; ++w) {
            float v = bestv_s[w][t];
            int   ix = besti_s[w][t];
            if (v < bv || (v == bv && ix < bi)) { bv = v; bi = ix; }
        }
        float x2 = 0.f;
#pragma unroll
        for (int s = 0; s < 8; ++s) x2 += x2p[t][s];
        float dm = x2 + bv;
        int n = (blk << 6) + t;
        ind_out[n] = (float)bi;
        float nr = fmaxf(sqrtf(snorm[t]), 1e-9f);
        scale_s[t] = sqrtf(fmaxf(dm, 0.f)) / nr;
    }
    __syncthreads();

    // ---- z_q write (coalesced, z from LDS) + loss partials ----
    float acc = 0.f;
    const size_t obase = ((size_t)b << 16) + hw0;
#pragma unroll
    for (int it = 0; it < 8; ++it) {
        int flat = it * 512 + t;
        int d = flat >> 6;               // wave-uniform
        int c = t & 63;
        float v = zt[c][d] + nt[d][c] * scale_s[c];
        zq[obase + (size_t)d * HW + c] = v;
        acc += v;
    }

    partials[t] = acc;
    __syncthreads();
    if (t < 4) {
        float s = 0.f;
        for (int g = 0; g < 8; ++g)
            for (int j = 0; j < 16; ++j)
                s += partials[g * 64 + t * 16 + j];
        sq[t] = s * s;
    }
    __syncthreads();
    if (t == 0) {
        float contrib = (sq[0] + sq[1] + sq[2] + sq[3]) * (1.0f / 33554432.0f);
        atomicAdd(loss_slot, contrib);
    }
}

// ---------------------------------------------------------------------------
extern "C" void kernel_launch(void* const* d_in, const int* in_sizes, int n_in,
                              void* d_out, int out_size, void* d_ws, size_t ws_size,
                              hipStream_t stream) {
    const float* z        = (const float*)d_in[0];   // (32,64,32,32)
    const float* codebook = (const float*)d_in[1];   // (1024,64)
    const float* noise    = (const float*)d_in[2];   // (32768,64)

    float* out      = (float*)d_out;
    float* zq_out   = out;                 // 2097152 floats
    float* loss_ptr = out + 2097152;       // 1 float
    float* ind_out  = out + 2097153;       // 32768 floats

    float* y2       = (float*)d_ws;             // 1024 floats
    _Float16* ch    = (_Float16*)(y2 + MM);     // 65536 halves (128KB)
    _Float16* cl    = ch + 65536;               // 65536 halves (128KB)

    k_prep<<<16,  512, 0, stream>>>(codebook, ch, cl, y2, loss_ptr);
    k_main<<<512, 512, 0, stream>>>(z, noise, ch, cl, y2,
                                    zq_out, ind_out, loss_ptr);
}